// Round 9
// baseline (4739.952 us; speedup 1.0000x reference)
//
#include <hip/hip_runtime.h>
#include <cstdint>
#include <cmath>

typedef unsigned short u16;
typedef unsigned int u32;
typedef __attribute__((ext_vector_type(8))) short bf16x8;
typedef __attribute__((ext_vector_type(4))) float f32x4;

// ---- model dims ----
#define B_    8
#define T_IN  2048
#define CIN1  273
#define L1_   1025
#define L_    513
#define C_    512
#define CE_   576
#define M1_   (B_*L1_)   /* 8200 */
#define M_    (B_*L_)    /* 4104 */
#define K1_   (CIN1*4)   /* 1092 */
#define H_    8
#define D_    64
#define R_    50

__device__ __forceinline__ u32 f2bf_rne(float f) {
    u32 x = __float_as_uint(f);
    return (x + 0x7fffu + ((x >> 16) & 1u)) >> 16;
}

// ======================= A-element loader =======================
// amode: 0 = fp32 row-major A (lda), 2 = conv1 im2col from meg, 3 = conv2 im2col from x1,
//        4 = time-major h [t][b][c] read as A[m=b*L+t][k=c]
__device__ __forceinline__ float a_load(const void* A, int m, int k, int lda, int amode) {
    if (amode == 0) {
        return ((const float*)A)[(size_t)m * lda + k];
    } else if (amode == 2) {
        int b = m / L1_, t = m - b * L1_;
        int ci = k >> 2, kk = k & 3;
        int it = 2 * t - 2 + kk;
        if ((unsigned)it >= (unsigned)T_IN) return 0.f;
        return ((const float*)A)[((size_t)(b * CIN1 + ci)) * T_IN + it];
    } else if (amode == 3) {
        int b = m / L_, t = m - b * L_;
        int ci = k >> 2, kk = k & 3;
        int it = 2 * t - 2 + kk;
        if ((unsigned)it >= (unsigned)L1_) return 0.f;
        return ((const float*)A)[((size_t)(b * L1_ + it)) * C_ + ci];
    } else {
        int b = m / L_, t = m - b * L_;
        return ((const float*)A)[((size_t)(t * 8 + b)) * C_ + k];
    }
}

// ======================= MFMA GEMM: C[m,n] = sum_k A[m,k]*B[n,k] + bias =======================
// 64x64 tile, K-step 32, bf16 inputs / fp32 accumulate.
// cmode: 0 = C[m*ldc+n]; 1 = out[b][n][t] (n<128); 2 = C[(t*8+b)*ldc+n] (time-major)
__global__ __launch_bounds__(256) void gemm_kernel(
    const void* __restrict__ Aptr, const float* __restrict__ Bptr,
    const float* __restrict__ bias1, const float* __restrict__ bias2,
    float* __restrict__ Cf,
    int Msz, int Nsz, int Ksz, int lda, int ldc, int amode, int cmode, int relu)
{
    __shared__ u16 As[64][40];
    __shared__ u16 Bs[64][40];

    int tid = threadIdx.x;
    int m0 = blockIdx.x * 64, n0 = blockIdx.y * 64;
    int wv = tid >> 6, lane = tid & 63;
    int lm = lane & 15, quad = lane >> 4;

    int kp = tid & 15;
    int rw = tid >> 4;

    f32x4 acc[4];
#pragma unroll
    for (int nt = 0; nt < 4; ++nt)
#pragma unroll
        for (int r = 0; r < 4; ++r) acc[nt][r] = 0.f;

    for (int k0 = 0; k0 < Ksz; k0 += 32) {
#pragma unroll
        for (int i = 0; i < 4; ++i) {
            int row = rw + 16 * i;
            int k = k0 + 2 * kp;
            int m = m0 + row;
            float a0 = 0.f, a1 = 0.f;
            if (m < Msz) {
                if (k < Ksz)     a0 = a_load(Aptr, m, k, lda, amode);
                if (k + 1 < Ksz) a1 = a_load(Aptr, m, k + 1, lda, amode);
            }
            *(u32*)&As[row][2 * kp] = f2bf_rne(a0) | (f2bf_rne(a1) << 16);
            int n = n0 + row;
            float b0 = 0.f, b1 = 0.f;
            if (k < Ksz)     b0 = Bptr[(size_t)n * Ksz + k];
            if (k + 1 < Ksz) b1 = Bptr[(size_t)n * Ksz + k + 1];
            *(u32*)&Bs[row][2 * kp] = f2bf_rne(b0) | (f2bf_rne(b1) << 16);
        }
        __syncthreads();

        bf16x8 af = *(const bf16x8*)&As[wv * 16 + lm][quad * 8];
#pragma unroll
        for (int nt = 0; nt < 4; ++nt) {
            bf16x8 bf = *(const bf16x8*)&Bs[nt * 16 + lm][quad * 8];
            acc[nt] = __builtin_amdgcn_mfma_f32_16x16x32_bf16(af, bf, acc[nt], 0, 0, 0);
        }
        __syncthreads();
    }

#pragma unroll
    for (int nt = 0; nt < 4; ++nt) {
#pragma unroll
        for (int r = 0; r < 4; ++r) {
            int m = m0 + wv * 16 + quad * 4 + r;
            if (m >= Msz) continue;
            int n = n0 + nt * 16 + lm;
            float v = acc[nt][r] + bias1[n] + (bias2 ? bias2[n] : 0.f);
            if (relu) v = fmaxf(v, 0.f);
            if (cmode == 0) {
                Cf[(size_t)m * ldc + n] = v;
            } else if (cmode == 1) {
                int b = m / L_, t = m - b * L_;
                Cf[((size_t)(b * 128 + n)) * L_ + t] = v;
            } else {
                int b = m / L_, t = m - b * L_;
                Cf[((size_t)(t * 8 + b)) * ldc + n] = v;
            }
        }
    }
}

// ======================= fused q/k/cnt projection GEMM (amode=4 A, 3 outputs) ===================
__global__ __launch_bounds__(256) void gemm_qkv(
    const float* __restrict__ h1tm,
    const float* __restrict__ qw, const float* __restrict__ kw, const float* __restrict__ cw,
    const float* __restrict__ qb, const float* __restrict__ kb, const float* __restrict__ cb,
    float* __restrict__ qo, float* __restrict__ ko, float* __restrict__ co)
{
    __shared__ u16 As[64][40];
    __shared__ u16 Bs[64][40];

    int tid = threadIdx.x;
    int which = blockIdx.y >> 3;
    int m0 = blockIdx.x * 64, n0 = (blockIdx.y & 7) * 64;
    const float* Bptr = which == 0 ? qw : (which == 1 ? kw : cw);
    const float* bias = which == 0 ? qb : (which == 1 ? kb : cb);
    float* Cf = which == 0 ? qo : (which == 1 ? ko : co);

    int wv = tid >> 6, lane = tid & 63;
    int lm = lane & 15, quad = lane >> 4;
    int kp = tid & 15, rw = tid >> 4;

    f32x4 acc[4];
#pragma unroll
    for (int nt = 0; nt < 4; ++nt)
#pragma unroll
        for (int r = 0; r < 4; ++r) acc[nt][r] = 0.f;

    for (int k0 = 0; k0 < 512; k0 += 32) {
#pragma unroll
        for (int i = 0; i < 4; ++i) {
            int row = rw + 16 * i;
            int k = k0 + 2 * kp;
            int m = m0 + row;
            float a0 = 0.f, a1 = 0.f;
            if (m < M_) {
                int b = m / L_, t = m - b * L_;
                const float* ap = &h1tm[((size_t)(t * 8 + b)) * C_ + k];
                a0 = ap[0]; a1 = ap[1];
            }
            *(u32*)&As[row][2 * kp] = f2bf_rne(a0) | (f2bf_rne(a1) << 16);
            int n = n0 + row;
            float b0 = Bptr[(size_t)n * 512 + k];
            float b1 = Bptr[(size_t)n * 512 + k + 1];
            *(u32*)&Bs[row][2 * kp] = f2bf_rne(b0) | (f2bf_rne(b1) << 16);
        }
        __syncthreads();

        bf16x8 af = *(const bf16x8*)&As[wv * 16 + lm][quad * 8];
#pragma unroll
        for (int nt = 0; nt < 4; ++nt) {
            bf16x8 bf = *(const bf16x8*)&Bs[nt * 16 + lm][quad * 8];
            acc[nt] = __builtin_amdgcn_mfma_f32_16x16x32_bf16(af, bf, acc[nt], 0, 0, 0);
        }
        __syncthreads();
    }

#pragma unroll
    for (int nt = 0; nt < 4; ++nt) {
#pragma unroll
        for (int r = 0; r < 4; ++r) {
            int m = m0 + wv * 16 + quad * 4 + r;
            if (m >= M_) continue;
            int n = n0 + nt * 16 + lm;
            Cf[(size_t)m * 512 + n] = acc[nt][r] + bias[n];
        }
    }
}

// ======================= subject embedding concat =======================
__global__ __launch_bounds__(256) void emb_kernel(const float* __restrict__ semb,
                                                  const int* __restrict__ subj,
                                                  float* __restrict__ x2bt)
{
    int idx = blockIdx.x * 256 + threadIdx.x;
    if (idx >= M_ * 64) return;
    int m = idx >> 6, e = idx & 63;
    int b = m / L_;
    x2bt[(size_t)m * CE_ + 512 + e] = semb[subj[b] * 64 + e];
}

// ======================= weight pack: fp32 [2048][512] -> bf16x2 u32 =======================
// layout: P[j][g][i2][lane][r], flat = ((j*4+g)*2+i2)*128 + lane*2 + r.
__global__ __launch_bounds__(256) void pack_w(const float* __restrict__ W, u32* __restrict__ P)
{
    int gid = blockIdx.x * 256 + threadIdx.x;   // 524288 total
    int r = gid & 1, lane = (gid >> 1) & 63, i2 = (gid >> 7) & 1;
    int g = (gid >> 8) & 3, j = gid >> 10;
    int row = g * 512 + j;
    int c0 = 4 * (lane + 64 * i2) + 2 * r;
    u32 lo = f2bf_rne(W[(size_t)row * 512 + c0]);
    u32 hi = f2bf_rne(W[(size_t)row * 512 + c0 + 1]);
    P[gid] = lo | (hi << 16);
}

// ======================= 3-way balanced LSTM step =======================
// Launch t = 0..514. Grid 384 = 3 x 128 blocks; every block does ONE 512-wide matvec:
//  type0 (blk 0..127):   layer0 gates step s=t   : Whh0@h0(s-1) + pre0(s)      -> h0(s), c0
//  type1 (blk 128..255): pre1(s=t-1) = Wih1@h0(s) + bih1 + bhh1 -> ring slot s&1
//  type2 (blk 256..383): layer1 gates step s=t-2 : Whh1@h1(s-1) + pre1ring(s)  -> h1(s), c1
// All producer->consumer edges cross launch boundaries; ring slots alternate by parity.
// Wave rg owns hidden unit j = blk*4+rg (all 4 gates, all 8 batches); h layout [t][b][c].
__global__ __launch_bounds__(256, 1) void lstm_step3(
    const float* __restrict__ pre0,
    const u32* __restrict__ P0,    // Whh0 packed
    const u32* __restrict__ P1,    // Wih1 packed
    const u32* __restrict__ P2,    // Whh1 packed
    const float* __restrict__ bih1,
    const float* __restrict__ bhh1,
    float* __restrict__ h0seq,
    float* __restrict__ h1seq,
    float* __restrict__ c0st, float* __restrict__ c1st,
    float* __restrict__ pre1ring,   // [2][8][2048]
    int t)
{
    int type = blockIdx.x >> 7;
    int blk = blockIdx.x & 127;
    int tid = threadIdx.x;
    int l = tid & 63, rg = tid >> 6;
    int j = blk * 4 + rg;

    int s;
    const float* hbase;
    const u32* W;
    if (type == 0) {
        s = t; if (s >= L_) return;
        W = P0 + (size_t)j * 1024;
        hbase = (s > 0) ? h0seq + (size_t)(s - 1) * 4096 : nullptr;
    } else if (type == 1) {
        s = t - 1; if (s < 0 || s >= L_) return;
        W = P1 + (size_t)j * 1024;
        hbase = h0seq + (size_t)s * 4096;
    } else {
        s = t - 2; if (s < 0 || s >= L_) return;
        W = P2 + (size_t)j * 1024;
        hbase = (s > 0) ? h1seq + (size_t)(s - 1) * 4096 : nullptr;
    }

    __shared__ float part[4 * 8 * 33];
    __shared__ float gates[4 * 33];

    // hoist the additive term (overlaps with matvec loads)
    float mypre = 0.f;
    if (tid < 128) {
        int fw = tid >> 5, g = (tid & 31) >> 3, b = tid & 7;
        int grow = g * 512 + blk * 4 + fw;
        if (type == 0)      mypre = pre0[((size_t)(s * 8 + b)) * 2048 + grow];
        else if (type == 1) mypre = bih1[grow] + bhh1[grow];
        else                mypre = pre1ring[((size_t)((s & 1) * 8 + b)) * 2048 + grow];
    }

    float acc[4][8];
#pragma unroll
    for (int g = 0; g < 4; ++g)
#pragma unroll
        for (int b = 0; b < 8; ++b) acc[g][b] = 0.f;

    if (hbase) {
#pragma unroll
        for (int i2 = 0; i2 < 2; ++i2) {
            int coff = 4 * (l + 64 * i2);
            float4 hv[8];
#pragma unroll
            for (int b = 0; b < 8; ++b)
                hv[b] = *(const float4*)&hbase[b * 512 + coff];
#pragma unroll
            for (int g = 0; g < 4; ++g) {
                uint2 ww = *(const uint2*)&W[(g * 2 + i2) * 128 + l * 2];
                float w0 = __uint_as_float(ww.x << 16);
                float w1 = __uint_as_float(ww.x & 0xffff0000u);
                float w2 = __uint_as_float(ww.y << 16);
                float w3 = __uint_as_float(ww.y & 0xffff0000u);
#pragma unroll
                for (int b = 0; b < 8; ++b)
                    acc[g][b] = fmaf(w0, hv[b].x, fmaf(w1, hv[b].y,
                                fmaf(w2, hv[b].z, fmaf(w3, hv[b].w, acc[g][b]))));
            }
        }
    }

    // butterfly over lane bits 3..5; lanes 0..7 hold partials
#pragma unroll
    for (int m = 8; m <= 32; m <<= 1)
#pragma unroll
        for (int g = 0; g < 4; ++g)
#pragma unroll
            for (int b = 0; b < 8; ++b)
                acc[g][b] += __shfl_xor(acc[g][b], m);
    if (l < 8) {
#pragma unroll
        for (int g = 0; g < 4; ++g)
#pragma unroll
            for (int b = 0; b < 8; ++b)
                part[(rg * 8 + l) * 33 + g * 8 + b] = acc[g][b];
    }
    __syncthreads();

    // combine 8 partials + additive term
    if (tid < 128) {
        int w = tid >> 5, x = tid & 31;
        int g = x >> 3, b = x & 7;
        float sum = 0.f;
#pragma unroll
        for (int p = 0; p < 8; ++p) sum += part[(w * 8 + p) * 33 + x];
        sum += mypre;
        if (type == 1)
            pre1ring[((size_t)((s & 1) * 8 + b)) * 2048 + g * 512 + blk * 4 + w] = sum;
        else
            gates[w * 33 + x] = sum;
    }
    if (type == 1) return;
    __syncthreads();

    // gate math + writes
    if (tid < 32) {
        int w = tid >> 3, b = tid & 7;
        float gi = gates[w * 33 + 0 * 8 + b];
        float gf = gates[w * 33 + 1 * 8 + b];
        float gg = gates[w * 33 + 2 * 8 + b];
        float go = gates[w * 33 + 3 * 8 + b];
        float* cst = (type == 0) ? c0st : c1st;
        int ji = blk * 4 + w;
        int ci = b * 512 + ji;
        float cprev = (s == 0) ? 0.f : cst[ci];
        float si = 1.f / (1.f + expf(-gi));
        float sf = 1.f / (1.f + expf(-gf));
        float so = 1.f / (1.f + expf(-go));
        float cn = sf * cprev + si * tanhf(gg);
        cst[ci] = cn;
        float* hout = (type == 0) ? h0seq : h1seq;
        hout[((size_t)s * 8 + b) * 512 + ji] = so * tanhf(cn);
    }
}

// ======================= banded attention (radius 50) =======================
__global__ __launch_bounds__(128) void attn_kernel(const float* __restrict__ q,
                                                   const float* __restrict__ k,
                                                   const float* __restrict__ cnt,
                                                   const float* __restrict__ rel,
                                                   float* __restrict__ out)
{
    int t = blockIdx.x, h = blockIdx.y, b = blockIdx.z;
    int s_lo = max(0, t - R_), s_hi = min(L_ - 1, t + R_);
    int W = s_hi - s_lo + 1;
    int tid = threadIdx.x;

    __shared__ float qrow[64];
    __shared__ float dots[104];
    __shared__ float red[128];

    const float* qp = q + ((size_t)(b * L_ + t) * C_ + h * D_);
    if (tid < 64) qrow[tid] = qp[tid];
    __syncthreads();

    if (tid < W) {
        int s = s_lo + tid;
        const float* kp = k + ((size_t)(b * L_ + s) * C_ + h * D_);
        const float* rp = rel + (R_ + t - s) * D_;
        float acc = 0.f;
#pragma unroll 8
        for (int d = 0; d < 64; ++d)
            acc += qrow[d] * (kp[d] + 0.3f * rp[d]);
        dots[tid] = acc;
    }
    __syncthreads();

    red[tid] = (tid < W) ? dots[tid] : -INFINITY;
    __syncthreads();
    for (int s = 64; s > 0; s >>= 1) {
        if (tid < s) red[tid] = fmaxf(red[tid], red[tid + s]);
        __syncthreads();
    }
    float mx = red[0];
    __syncthreads();
    float e = 0.f;
    if (tid < W) { e = expf(dots[tid] - mx); dots[tid] = e; }
    red[tid] = e;
    __syncthreads();
    for (int s = 64; s > 0; s >>= 1) {
        if (tid < s) red[tid] += red[tid + s];
        __syncthreads();
    }
    float inv = 1.f / red[0];
    if (tid < W) dots[tid] *= inv;
    __syncthreads();

    if (tid < 64) {
        float acc = 0.f;
        const float* cb = cnt + ((size_t)(b * L_ + s_lo) * C_ + h * D_ + tid);
        const float* rb = rel + (R_ + t - s_lo) * D_ + tid;
        for (int i = 0; i < W; ++i)
            acc += dots[i] * (cb[(size_t)i * C_] + 0.3f * rb[-i * D_]);
        out[(size_t)(b * L_ + t) * C_ + h * D_ + tid] = acc;
    }
}

// ======================= BatchNorm training stats =======================
__global__ __launch_bounds__(256) void bn_stats(const float* __restrict__ fcout, float* __restrict__ stats)
{
    int o = blockIdx.x;
    int tid = threadIdx.x;
    float s = 0.f, ss = 0.f;
    for (int m = tid; m < M_; m += 256) {
        float v = fcout[(size_t)m * 512 + o];
        s += v; ss += v * v;
    }
    __shared__ float rs[256], rq[256];
    rs[tid] = s; rq[tid] = ss;
    __syncthreads();
    for (int k = 128; k > 0; k >>= 1) {
        if (tid < k) { rs[tid] += rs[tid + k]; rq[tid] += rq[tid + k]; }
        __syncthreads();
    }
    if (tid == 0) {
        float mean = rs[0] / (float)M_;
        float var = rq[0] / (float)M_ - mean * mean;
        stats[o] = mean;
        stats[512 + o] = rsqrtf(fmaxf(var, 0.f) + 1e-5f);
    }
}

// ======================= BN apply + ReLU*scale + residual (h1 time-major -> xfin batch-major) ====
__global__ __launch_bounds__(256) void bn_apply(const float* __restrict__ fcout,
                                                const float* __restrict__ stats,
                                                const float* __restrict__ bng, const float* __restrict__ bnb,
                                                const float* __restrict__ ascl,
                                                const float* __restrict__ h1tm,
                                                float* __restrict__ xfin)
{
    int idx = blockIdx.x * 256 + threadIdx.x;
    if (idx >= M_ * 512) return;
    int c = idx & 511;
    int m = idx >> 9;
    int b = m / L_, t = m - b * L_;
    float v = (fcout[idx] - stats[c]) * stats[512 + c] * bng[c] + bnb[c];
    v = fmaxf(v, 0.f) * ascl[c];
    xfin[idx] = h1tm[((size_t)(t * 8 + b)) * 512 + c] + v;
}

// ======================= host launch =======================
extern "C" void kernel_launch(void* const* d_in, const int* in_sizes, int n_in,
                              void* d_out, int out_size, void* d_ws, size_t ws_size,
                              hipStream_t stream)
{
    const float* meg  = (const float*)d_in[0];
    const float* w1   = (const float*)d_in[1];
    const float* b1   = (const float*)d_in[2];
    const float* w2   = (const float*)d_in[3];
    const float* b2   = (const float*)d_in[4];
    const float* semb = (const float*)d_in[5];
    const float* Wih0 = (const float*)d_in[6];
    const float* Whh0 = (const float*)d_in[7];
    const float* bih0 = (const float*)d_in[8];
    const float* bhh0 = (const float*)d_in[9];
    const float* Wih1 = (const float*)d_in[10];
    const float* Whh1 = (const float*)d_in[11];
    const float* bih1 = (const float*)d_in[12];
    const float* bhh1 = (const float*)d_in[13];
    const float* qw   = (const float*)d_in[14];
    const float* qb   = (const float*)d_in[15];
    const float* kw   = (const float*)d_in[16];
    const float* kb   = (const float*)d_in[17];
    const float* cw   = (const float*)d_in[18];
    const float* cbi  = (const float*)d_in[19];
    const float* rel  = (const float*)d_in[20];
    const float* fcw  = (const float*)d_in[21];
    const float* fcb  = (const float*)d_in[22];
    const float* bng  = (const float*)d_in[23];
    const float* bnb  = (const float*)d_in[24];
    const float* ascl = (const float*)d_in[25];
    const float* outw = (const float*)d_in[26];
    const float* outb = (const float*)d_in[27];
    const int* subj = (const int*)d_in[28];
    float* out = (float*)d_out;

    float* ws = (float*)d_ws;
    // arena (float offsets)
    float* x1    = ws + 0;          // [8200][512] conv phase only -> 4,198,400
    // LSTM-phase overlays of the dead x1 region:
    u32*   P0    = (u32*)(ws + 0);        // Whh0 bf16 packed: 524,288 words
    u32*   P1    = (u32*)(ws + 524288);   // Wih1
    u32*   P2    = (u32*)(ws + 1048576);  // Whh1
    float* c0    = ws + 1572864;    // [8][512] cell state L0
    float* c1    = ws + 1576960;    // [8][512] cell state L1
    float* pre1r = ws + 1581056;    // [2][8][2048] ring           -> 1,613,824
    float* x2bt  = ws + 4198400;    // [4104][576]                 -> 6,562,304
    float* pre0  = ws + 6562304;    // [(t*8+b)][2048]             -> 14,967,296
    float* h0    = ws + 14967296;   // [t][b][c]                   -> 17,068,544
    float* h1    = ws + 17068544;   // [t][b][c]                   -> 19,169,792
    float* xfin  = ws + 19169792;   // [b*L+t][c] final residual   -> 21,271,040
    // post-LSTM overlays:
    float* qb_f  = ws + 0;          // q  [4104][512]
    float* kb_f  = ws + 2101248;    // k
    float* cb_f  = ws + 4202496;    // cnt (spills into dead x2bt region)
    float* attno = ws + 6562304;    // over pre0
    float* fco   = ws + 8663552;
    float* stats = ws + 10764800;   // 1024 floats

    auto gemm = [&](const void* A, const float* Bw, const float* bi1, const float* bi2,
                    float* Cf, int Msz, int Nsz, int Ksz,
                    int lda, int ldc, int amode, int cmode, int relu) {
        dim3 g((Msz + 63) / 64, Nsz / 64);
        gemm_kernel<<<g, 256, 0, stream>>>(A, Bw, bi1, bi2, Cf,
                                           Msz, Nsz, Ksz, lda, ldc, amode, cmode, relu);
    };

    // conv1 (im2col from meg) -> x1 [b*1025+t][512], relu
    gemm(meg, w1, b1, nullptr, x1, M1_, 512, K1_, 0, 512, 2, 0, 1);
    // conv2 (im2col from x1) -> x2bt [b*513+t][576] cols 0..511, relu
    gemm(x1, w2, b2, nullptr, x2bt, M_, 512, 2048, 0, CE_, 3, 0, 1);
    // subject embedding -> cols 512..575
    emb_kernel<<<(M_ * 64 + 255) / 256, 256, 0, stream>>>(semb, subj, x2bt);

    // pack LSTM weights to bf16 (x1 region is dead now)
    pack_w<<<2048, 256, 0, stream>>>(Whh0, P0);
    pack_w<<<2048, 256, 0, stream>>>(Wih1, P1);
    pack_w<<<2048, 256, 0, stream>>>(Whh1, P2);

    // layer-0 x-projection (time-major output, both biases folded)
    gemm(x2bt, Wih0, bih0, bhh0, pre0, M_, 2048, CE_, CE_, 2048, 0, 2, 0);

    // 3-way balanced LSTM: 515 launches
    for (int t = 0; t <= L_ + 1; ++t)
        lstm_step3<<<384, 256, 0, stream>>>(pre0, P0, P1, P2, bih1, bhh1,
                                            h0, h1, c0, c1, pre1r, t);

    // fused q/k/cnt projections (read h1 time-major)
    gemm_qkv<<<dim3((M_ + 63) / 64, 24), 256, 0, stream>>>(h1, qw, kw, cw, qb, kb, cbi,
                                                           qb_f, kb_f, cb_f);

    attn_kernel<<<dim3(L_, H_, B_), 128, 0, stream>>>(qb_f, kb_f, cb_f, rel, attno);

    // fc + BN(train) + relu*scale + residual -> xfin (batch-major)
    gemm(attno, fcw, fcb, nullptr, fco, M_, 512, 512, 512, 512, 0, 0, 0);
    bn_stats<<<512, 256, 0, stream>>>(fco, stats);
    bn_apply<<<(M_ * 512 + 255) / 256, 256, 0, stream>>>(fco, stats, bng, bnb, ascl, h1, xfin);

    // final projection -> d_out [b][128][t] fp32
    gemm(xfin, outw, outb, nullptr, out, M_, 128, 512, 512, 0, 0, 1, 0);
}

// Round 10
// 4545.135 us; speedup vs baseline: 1.0429x; 1.0429x over previous
//
#include <hip/hip_runtime.h>
#include <cstdint>
#include <cmath>

typedef unsigned short u16;
typedef unsigned int u32;
typedef __attribute__((ext_vector_type(8))) short bf16x8;
typedef __attribute__((ext_vector_type(4))) float f32x4;

// ---- model dims ----
#define B_    8
#define T_IN  2048
#define CIN1  273
#define L1_   1025
#define L_    513
#define C_    512
#define CE_   576
#define M1_   (B_*L1_)   /* 8200 */
#define M_    (B_*L_)    /* 4104 */
#define K1_   (CIN1*4)   /* 1092 */
#define H_    8
#define D_    64
#define R_    50

__device__ __forceinline__ u32 f2bf_rne(float f) {
    u32 x = __float_as_uint(f);
    return (x + 0x7fffu + ((x >> 16) & 1u)) >> 16;
}

// ======================= A-element loader =======================
// amode: 0 = fp32 row-major A (lda), 2 = conv1 im2col from meg, 3 = conv2 im2col from x1,
//        4 = time-major h [t][b][c] read as A[m=b*L+t][k=c]
__device__ __forceinline__ float a_load(const void* A, int m, int k, int lda, int amode) {
    if (amode == 0) {
        return ((const float*)A)[(size_t)m * lda + k];
    } else if (amode == 2) {
        int b = m / L1_, t = m - b * L1_;
        int ci = k >> 2, kk = k & 3;
        int it = 2 * t - 2 + kk;
        if ((unsigned)it >= (unsigned)T_IN) return 0.f;
        return ((const float*)A)[((size_t)(b * CIN1 + ci)) * T_IN + it];
    } else if (amode == 3) {
        int b = m / L_, t = m - b * L_;
        int ci = k >> 2, kk = k & 3;
        int it = 2 * t - 2 + kk;
        if ((unsigned)it >= (unsigned)L1_) return 0.f;
        return ((const float*)A)[((size_t)(b * L1_ + it)) * C_ + ci];
    } else {
        int b = m / L_, t = m - b * L_;
        return ((const float*)A)[((size_t)(t * 8 + b)) * C_ + k];
    }
}

// ======================= MFMA GEMM: C[m,n] = sum_k A[m,k]*B[n,k] + bias =======================
// 64x64 tile, K-step 32, bf16 inputs / fp32 accumulate.
// cmode: 0 = C[m*ldc+n]; 1 = out[b][n][t] (n<128); 2 = C[(t*8+b)*ldc+n] (time-major)
__global__ __launch_bounds__(256) void gemm_kernel(
    const void* __restrict__ Aptr, const float* __restrict__ Bptr,
    const float* __restrict__ bias1, const float* __restrict__ bias2,
    float* __restrict__ Cf,
    int Msz, int Nsz, int Ksz, int lda, int ldc, int amode, int cmode, int relu)
{
    __shared__ u16 As[64][40];
    __shared__ u16 Bs[64][40];

    int tid = threadIdx.x;
    int m0 = blockIdx.x * 64, n0 = blockIdx.y * 64;
    int wv = tid >> 6, lane = tid & 63;
    int lm = lane & 15, quad = lane >> 4;

    int kp = tid & 15;
    int rw = tid >> 4;

    f32x4 acc[4];
#pragma unroll
    for (int nt = 0; nt < 4; ++nt)
#pragma unroll
        for (int r = 0; r < 4; ++r) acc[nt][r] = 0.f;

    for (int k0 = 0; k0 < Ksz; k0 += 32) {
#pragma unroll
        for (int i = 0; i < 4; ++i) {
            int row = rw + 16 * i;
            int k = k0 + 2 * kp;
            int m = m0 + row;
            float a0 = 0.f, a1 = 0.f;
            if (m < Msz) {
                if (k < Ksz)     a0 = a_load(Aptr, m, k, lda, amode);
                if (k + 1 < Ksz) a1 = a_load(Aptr, m, k + 1, lda, amode);
            }
            *(u32*)&As[row][2 * kp] = f2bf_rne(a0) | (f2bf_rne(a1) << 16);
            int n = n0 + row;
            float b0 = 0.f, b1 = 0.f;
            if (k < Ksz)     b0 = Bptr[(size_t)n * Ksz + k];
            if (k + 1 < Ksz) b1 = Bptr[(size_t)n * Ksz + k + 1];
            *(u32*)&Bs[row][2 * kp] = f2bf_rne(b0) | (f2bf_rne(b1) << 16);
        }
        __syncthreads();

        bf16x8 af = *(const bf16x8*)&As[wv * 16 + lm][quad * 8];
#pragma unroll
        for (int nt = 0; nt < 4; ++nt) {
            bf16x8 bf = *(const bf16x8*)&Bs[nt * 16 + lm][quad * 8];
            acc[nt] = __builtin_amdgcn_mfma_f32_16x16x32_bf16(af, bf, acc[nt], 0, 0, 0);
        }
        __syncthreads();
    }

#pragma unroll
    for (int nt = 0; nt < 4; ++nt) {
#pragma unroll
        for (int r = 0; r < 4; ++r) {
            int m = m0 + wv * 16 + quad * 4 + r;
            if (m >= Msz) continue;
            int n = n0 + nt * 16 + lm;
            float v = acc[nt][r] + bias1[n] + (bias2 ? bias2[n] : 0.f);
            if (relu) v = fmaxf(v, 0.f);
            if (cmode == 0) {
                Cf[(size_t)m * ldc + n] = v;
            } else if (cmode == 1) {
                int b = m / L_, t = m - b * L_;
                Cf[((size_t)(b * 128 + n)) * L_ + t] = v;
            } else {
                int b = m / L_, t = m - b * L_;
                Cf[((size_t)(t * 8 + b)) * ldc + n] = v;
            }
        }
    }
}

// ======================= fused q/k/cnt projection GEMM (time-major A, 3 outputs) ===============
__global__ __launch_bounds__(256) void gemm_qkv(
    const float* __restrict__ h1tm,
    const float* __restrict__ qw, const float* __restrict__ kw, const float* __restrict__ cw,
    const float* __restrict__ qb, const float* __restrict__ kb, const float* __restrict__ cb,
    float* __restrict__ qo, float* __restrict__ ko, float* __restrict__ co)
{
    __shared__ u16 As[64][40];
    __shared__ u16 Bs[64][40];

    int tid = threadIdx.x;
    int which = blockIdx.y >> 3;
    int m0 = blockIdx.x * 64, n0 = (blockIdx.y & 7) * 64;
    const float* Bptr = which == 0 ? qw : (which == 1 ? kw : cw);
    const float* bias = which == 0 ? qb : (which == 1 ? kb : cb);
    float* Cf = which == 0 ? qo : (which == 1 ? ko : co);

    int wv = tid >> 6, lane = tid & 63;
    int lm = lane & 15, quad = lane >> 4;
    int kp = tid & 15, rw = tid >> 4;

    f32x4 acc[4];
#pragma unroll
    for (int nt = 0; nt < 4; ++nt)
#pragma unroll
        for (int r = 0; r < 4; ++r) acc[nt][r] = 0.f;

    for (int k0 = 0; k0 < 512; k0 += 32) {
#pragma unroll
        for (int i = 0; i < 4; ++i) {
            int row = rw + 16 * i;
            int k = k0 + 2 * kp;
            int m = m0 + row;
            float a0 = 0.f, a1 = 0.f;
            if (m < M_) {
                int b = m / L_, t = m - b * L_;
                const float* ap = &h1tm[((size_t)(t * 8 + b)) * C_ + k];
                a0 = ap[0]; a1 = ap[1];
            }
            *(u32*)&As[row][2 * kp] = f2bf_rne(a0) | (f2bf_rne(a1) << 16);
            int n = n0 + row;
            float b0 = Bptr[(size_t)n * 512 + k];
            float b1 = Bptr[(size_t)n * 512 + k + 1];
            *(u32*)&Bs[row][2 * kp] = f2bf_rne(b0) | (f2bf_rne(b1) << 16);
        }
        __syncthreads();

        bf16x8 af = *(const bf16x8*)&As[wv * 16 + lm][quad * 8];
#pragma unroll
        for (int nt = 0; nt < 4; ++nt) {
            bf16x8 bf = *(const bf16x8*)&Bs[nt * 16 + lm][quad * 8];
            acc[nt] = __builtin_amdgcn_mfma_f32_16x16x32_bf16(af, bf, acc[nt], 0, 0, 0);
        }
        __syncthreads();
    }

#pragma unroll
    for (int nt = 0; nt < 4; ++nt) {
#pragma unroll
        for (int r = 0; r < 4; ++r) {
            int m = m0 + wv * 16 + quad * 4 + r;
            if (m >= M_) continue;
            int n = n0 + nt * 16 + lm;
            Cf[(size_t)m * 512 + n] = acc[nt][r] + bias[n];
        }
    }
}

// ======================= subject embedding concat =======================
__global__ __launch_bounds__(256) void emb_kernel(const float* __restrict__ semb,
                                                  const int* __restrict__ subj,
                                                  float* __restrict__ x2bt)
{
    int idx = blockIdx.x * 256 + threadIdx.x;
    if (idx >= M_ * 64) return;
    int m = idx >> 6, e = idx & 63;
    int b = m / L_;
    x2bt[(size_t)m * CE_ + 512 + e] = semb[subj[b] * 64 + e];
}

// ======================= weight pack: fp32 [2048][512] -> bf16x2 u32 =======================
// layout: P[j][g][i2][lane][r], flat = ((j*4+g)*2+i2)*128 + lane*2 + r.
__global__ __launch_bounds__(256) void pack_w(const float* __restrict__ W, u32* __restrict__ P)
{
    int gid = blockIdx.x * 256 + threadIdx.x;   // 524288 total
    int r = gid & 1, lane = (gid >> 1) & 63, i2 = (gid >> 7) & 1;
    int g = (gid >> 8) & 3, j = gid >> 10;
    int row = g * 512 + j;
    int c0 = 4 * (lane + 64 * i2) + 2 * r;
    u32 lo = f2bf_rne(W[(size_t)row * 512 + c0]);
    u32 hi = f2bf_rne(W[(size_t)row * 512 + c0 + 1]);
    P[gid] = lo | (hi << 16);
}

// ======================= fused 2-layer LSTM step (LDS-staged h, hoisted weights) ===============
// Launch t = 0..L_: blocks 0..127 = layer0 step t, blocks 128..255 = layer1 step t-1.
// Wave rg owns hidden unit j = blk*4+rg (all 4 gates, all 8 batches).
// h layout [t][b][c]. pre0[(t*8+b)*2048 + g*512+j] has x@Wih0 + bih0 + bhh0.
__global__ __launch_bounds__(256, 1) void lstm_step_fused(
    const float* __restrict__ pre0,
    const u32* __restrict__ P0,    // Whh0 packed
    const u32* __restrict__ P1,    // Wih1 packed
    const u32* __restrict__ P2,    // Whh1 packed
    const float* __restrict__ bih1,
    const float* __restrict__ bhh1,
    float* __restrict__ h0seq,
    float* __restrict__ h1seq,
    float* __restrict__ c0st, float* __restrict__ c1st,
    int t)
{
    int layer = blockIdx.x >> 7;
    int blk = blockIdx.x & 127;
    if (layer == 0 && t >= L_) return;
    if (layer == 1 && t == 0) return;
    int tt = layer ? (t - 1) : t;

    int tid = threadIdx.x;
    int l  = tid & 63;         // lane
    int rg = tid >> 6;         // wave = hidden-unit offset
    int j = blk * 4 + rg;

    __shared__ float4 hA4[1024];          // recurrent h(tt-1), [b][128] float4
    __shared__ float4 hB4[1024];          // layer1: h0(tt)
    __shared__ float part[4 * 8 * 33];
    __shared__ float gates[4 * 33];

    // ---- hoist weight loads (in flight during h staging) ----
    const u32* wA = (layer ? P2 : P0) + (size_t)j * 1024;
    uint2 wra[8], wrb[8];
#pragma unroll
    for (int i2 = 0; i2 < 2; ++i2)
#pragma unroll
        for (int g = 0; g < 4; ++g)
            wra[i2 * 4 + g] = *(const uint2*)&wA[(g * 2 + i2) * 128 + l * 2];
    if (layer) {
        const u32* wB = P1 + (size_t)j * 1024;
#pragma unroll
        for (int i2 = 0; i2 < 2; ++i2)
#pragma unroll
            for (int g = 0; g < 4; ++g)
                wrb[i2 * 4 + g] = *(const uint2*)&wB[(g * 2 + i2) * 128 + l * 2];
    }
    // ---- hoist additive term ----
    float mypre = 0.f;
    if (tid < 128) {
        int fw = tid >> 5, g = (tid & 31) >> 3, b = tid & 7;
        int grow = g * 512 + blk * 4 + fw;
        mypre = layer ? (bih1[grow] + bhh1[grow])
                      : pre0[((size_t)(tt * 8 + b)) * 2048 + grow];
    }

    // ---- stage h into LDS (once per block; kills 4x inter-wave redundancy) ----
    if (tt == 0) {
#pragma unroll
        for (int i = 0; i < 4; ++i)
            hA4[tid + 256 * i] = make_float4(0.f, 0.f, 0.f, 0.f);
    } else {
        const float4* src = (const float4*)((layer ? h1seq : h0seq) + (size_t)(tt - 1) * 4096);
#pragma unroll
        for (int i = 0; i < 4; ++i)
            hA4[tid + 256 * i] = src[tid + 256 * i];
    }
    if (layer) {
        const float4* src = (const float4*)(h0seq + (size_t)tt * 4096);
#pragma unroll
        for (int i = 0; i < 4; ++i)
            hB4[tid + 256 * i] = src[tid + 256 * i];
    }
    __syncthreads();

    float acc[4][8];
#pragma unroll
    for (int g = 0; g < 4; ++g)
#pragma unroll
        for (int b = 0; b < 8; ++b) acc[g][b] = 0.f;

    // ---- recurrent matvec from LDS + register weights ----
#pragma unroll
    for (int i2 = 0; i2 < 2; ++i2) {
        int cq = l + 64 * i2;
        float4 hv[8];
#pragma unroll
        for (int b = 0; b < 8; ++b) hv[b] = hA4[b * 128 + cq];
#pragma unroll
        for (int g = 0; g < 4; ++g) {
            uint2 ww = wra[i2 * 4 + g];
            float w0 = __uint_as_float(ww.x << 16);
            float w1 = __uint_as_float(ww.x & 0xffff0000u);
            float w2 = __uint_as_float(ww.y << 16);
            float w3 = __uint_as_float(ww.y & 0xffff0000u);
#pragma unroll
            for (int b = 0; b < 8; ++b)
                acc[g][b] = fmaf(w0, hv[b].x, fmaf(w1, hv[b].y,
                            fmaf(w2, hv[b].z, fmaf(w3, hv[b].w, acc[g][b]))));
        }
    }
    if (layer) {
#pragma unroll
        for (int i2 = 0; i2 < 2; ++i2) {
            int cq = l + 64 * i2;
            float4 hv[8];
#pragma unroll
            for (int b = 0; b < 8; ++b) hv[b] = hB4[b * 128 + cq];
#pragma unroll
            for (int g = 0; g < 4; ++g) {
                uint2 ww = wrb[i2 * 4 + g];
                float w0 = __uint_as_float(ww.x << 16);
                float w1 = __uint_as_float(ww.x & 0xffff0000u);
                float w2 = __uint_as_float(ww.y << 16);
                float w3 = __uint_as_float(ww.y & 0xffff0000u);
#pragma unroll
                for (int b = 0; b < 8; ++b)
                    acc[g][b] = fmaf(w0, hv[b].x, fmaf(w1, hv[b].y,
                                fmaf(w2, hv[b].z, fmaf(w3, hv[b].w, acc[g][b]))));
            }
        }
    }

    // ---- reduce over lanes: 3-level butterfly (bits 3..5), lanes 0..7 hold partials ----
#pragma unroll
    for (int m = 8; m <= 32; m <<= 1)
#pragma unroll
        for (int g = 0; g < 4; ++g)
#pragma unroll
            for (int b = 0; b < 8; ++b)
                acc[g][b] += __shfl_xor(acc[g][b], m);
    if (l < 8) {
#pragma unroll
        for (int g = 0; g < 4; ++g)
#pragma unroll
            for (int b = 0; b < 8; ++b)
                part[(rg * 8 + l) * 33 + g * 8 + b] = acc[g][b];
    }
    __syncthreads();

    // ---- sum 8 partials + x-side, store gates ----
    if (tid < 128) {
        int w = tid >> 5, x = tid & 31;
        float s = 0.f;
#pragma unroll
        for (int p = 0; p < 8; ++p) s += part[(w * 8 + p) * 33 + x];
        gates[w * 33 + x] = s + mypre;
    }
    __syncthreads();

    // ---- gate math + writes ----
    if (tid < 32) {
        int w = tid >> 3, b = tid & 7;
        float gi = gates[w * 33 + 0 * 8 + b];
        float gf = gates[w * 33 + 1 * 8 + b];
        float gg = gates[w * 33 + 2 * 8 + b];
        float go = gates[w * 33 + 3 * 8 + b];
        float* cst = layer ? c1st : c0st;
        int ji = blk * 4 + w;
        int ci = b * 512 + ji;
        float cprev = (tt == 0) ? 0.f : cst[ci];
        float si = 1.f / (1.f + expf(-gi));
        float sf = 1.f / (1.f + expf(-gf));
        float so = 1.f / (1.f + expf(-go));
        float cn = sf * cprev + si * tanhf(gg);
        cst[ci] = cn;
        float* hout = layer ? h1seq : h0seq;
        hout[((size_t)tt * 8 + b) * 512 + ji] = so * tanhf(cn);
    }
}

// ======================= banded attention (radius 50) =======================
__global__ __launch_bounds__(128) void attn_kernel(const float* __restrict__ q,
                                                   const float* __restrict__ k,
                                                   const float* __restrict__ cnt,
                                                   const float* __restrict__ rel,
                                                   float* __restrict__ out)
{
    int t = blockIdx.x, h = blockIdx.y, b = blockIdx.z;
    int s_lo = max(0, t - R_), s_hi = min(L_ - 1, t + R_);
    int W = s_hi - s_lo + 1;
    int tid = threadIdx.x;

    __shared__ float qrow[64];
    __shared__ float dots[104];
    __shared__ float red[128];

    const float* qp = q + ((size_t)(b * L_ + t) * C_ + h * D_);
    if (tid < 64) qrow[tid] = qp[tid];
    __syncthreads();

    if (tid < W) {
        int s = s_lo + tid;
        const float* kp = k + ((size_t)(b * L_ + s) * C_ + h * D_);
        const float* rp = rel + (R_ + t - s) * D_;
        float acc = 0.f;
#pragma unroll 8
        for (int d = 0; d < 64; ++d)
            acc += qrow[d] * (kp[d] + 0.3f * rp[d]);
        dots[tid] = acc;
    }
    __syncthreads();

    red[tid] = (tid < W) ? dots[tid] : -INFINITY;
    __syncthreads();
    for (int s = 64; s > 0; s >>= 1) {
        if (tid < s) red[tid] = fmaxf(red[tid], red[tid + s]);
        __syncthreads();
    }
    float mx = red[0];
    __syncthreads();
    float e = 0.f;
    if (tid < W) { e = expf(dots[tid] - mx); dots[tid] = e; }
    red[tid] = e;
    __syncthreads();
    for (int s = 64; s > 0; s >>= 1) {
        if (tid < s) red[tid] += red[tid + s];
        __syncthreads();
    }
    float inv = 1.f / red[0];
    if (tid < W) dots[tid] *= inv;
    __syncthreads();

    if (tid < 64) {
        float acc = 0.f;
        const float* cb = cnt + ((size_t)(b * L_ + s_lo) * C_ + h * D_ + tid);
        const float* rb = rel + (R_ + t - s_lo) * D_ + tid;
        for (int i = 0; i < W; ++i)
            acc += dots[i] * (cb[(size_t)i * C_] + 0.3f * rb[-i * D_]);
        out[(size_t)(b * L_ + t) * C_ + h * D_ + tid] = acc;
    }
}

// ======================= BatchNorm training stats =======================
__global__ __launch_bounds__(256) void bn_stats(const float* __restrict__ fcout, float* __restrict__ stats)
{
    int o = blockIdx.x;
    int tid = threadIdx.x;
    float s = 0.f, ss = 0.f;
    for (int m = tid; m < M_; m += 256) {
        float v = fcout[(size_t)m * 512 + o];
        s += v; ss += v * v;
    }
    __shared__ float rs[256], rq[256];
    rs[tid] = s; rq[tid] = ss;
    __syncthreads();
    for (int k = 128; k > 0; k >>= 1) {
        if (tid < k) { rs[tid] += rs[tid + k]; rq[tid] += rq[tid + k]; }
        __syncthreads();
    }
    if (tid == 0) {
        float mean = rs[0] / (float)M_;
        float var = rq[0] / (float)M_ - mean * mean;
        stats[o] = mean;
        stats[512 + o] = rsqrtf(fmaxf(var, 0.f) + 1e-5f);
    }
}

// ======================= BN apply + ReLU*scale + residual (h1 time-major -> xfin batch-major) ====
__global__ __launch_bounds__(256) void bn_apply(const float* __restrict__ fcout,
                                                const float* __restrict__ stats,
                                                const float* __restrict__ bng, const float* __restrict__ bnb,
                                                const float* __restrict__ ascl,
                                                const float* __restrict__ h1tm,
                                                float* __restrict__ xfin)
{
    int idx = blockIdx.x * 256 + threadIdx.x;
    if (idx >= M_ * 512) return;
    int c = idx & 511;
    int m = idx >> 9;
    int b = m / L_, t = m - b * L_;
    float v = (fcout[idx] - stats[c]) * stats[512 + c] * bng[c] + bnb[c];
    v = fmaxf(v, 0.f) * ascl[c];
    xfin[idx] = h1tm[((size_t)(t * 8 + b)) * 512 + c] + v;
}

// ======================= host launch =======================
extern "C" void kernel_launch(void* const* d_in, const int* in_sizes, int n_in,
                              void* d_out, int out_size, void* d_ws, size_t ws_size,
                              hipStream_t stream)
{
    const float* meg  = (const float*)d_in[0];
    const float* w1   = (const float*)d_in[1];
    const float* b1   = (const float*)d_in[2];
    const float* w2   = (const float*)d_in[3];
    const float* b2   = (const float*)d_in[4];
    const float* semb = (const float*)d_in[5];
    const float* Wih0 = (const float*)d_in[6];
    const float* Whh0 = (const float*)d_in[7];
    const float* bih0 = (const float*)d_in[8];
    const float* bhh0 = (const float*)d_in[9];
    const float* Wih1 = (const float*)d_in[10];
    const float* Whh1 = (const float*)d_in[11];
    const float* bih1 = (const float*)d_in[12];
    const float* bhh1 = (const float*)d_in[13];
    const float* qw   = (const float*)d_in[14];
    const float* qb   = (const float*)d_in[15];
    const float* kw   = (const float*)d_in[16];
    const float* kb   = (const float*)d_in[17];
    const float* cw   = (const float*)d_in[18];
    const float* cbi  = (const float*)d_in[19];
    const float* rel  = (const float*)d_in[20];
    const float* fcw  = (const float*)d_in[21];
    const float* fcb  = (const float*)d_in[22];
    const float* bng  = (const float*)d_in[23];
    const float* bnb  = (const float*)d_in[24];
    const float* ascl = (const float*)d_in[25];
    const float* outw = (const float*)d_in[26];
    const float* outb = (const float*)d_in[27];
    const int* subj = (const int*)d_in[28];
    float* out = (float*)d_out;

    float* ws = (float*)d_ws;
    // arena (float offsets)
    float* x1    = ws + 0;          // [8200][512] conv phase only -> 4,198,400
    // LSTM-phase overlays of the dead x1 region:
    u32*   P0    = (u32*)(ws + 0);        // Whh0 bf16 packed: 524,288 words
    u32*   P1    = (u32*)(ws + 524288);   // Wih1
    u32*   P2    = (u32*)(ws + 1048576);  // Whh1
    float* c0    = ws + 1572864;    // [8][512] cell state L0
    float* c1    = ws + 1576960;    // [8][512] cell state L1
    float* x2bt  = ws + 4198400;    // [4104][576]                 -> 6,562,304
    float* pre0  = ws + 6562304;    // [(t*8+b)][2048]             -> 14,967,296
    float* h0    = ws + 14967296;   // [t][b][c]                   -> 17,068,544
    float* h1    = ws + 17068544;   // [t][b][c]                   -> 19,169,792
    float* xfin  = ws + 19169792;   // [b*L+t][c] final residual   -> 21,271,040
    // post-LSTM overlays:
    float* qb_f  = ws + 0;          // q  [4104][512]
    float* kb_f  = ws + 2101248;    // k
    float* cb_f  = ws + 4202496;    // cnt (spills into dead x2bt region)
    float* attno = ws + 6562304;    // over pre0
    float* fco   = ws + 8663552;
    float* stats = ws + 10764800;   // 1024 floats

    auto gemm = [&](const void* A, const float* Bw, const float* bi1, const float* bi2,
                    float* Cf, int Msz, int Nsz, int Ksz,
                    int lda, int ldc, int amode, int cmode, int relu) {
        dim3 g((Msz + 63) / 64, Nsz / 64);
        gemm_kernel<<<g, 256, 0, stream>>>(A, Bw, bi1, bi2, Cf,
                                           Msz, Nsz, Ksz, lda, ldc, amode, cmode, relu);
    };

    // conv1 (im2col from meg) -> x1 [b*1025+t][512], relu
    gemm(meg, w1, b1, nullptr, x1, M1_, 512, K1_, 0, 512, 2, 0, 1);
    // conv2 (im2col from x1) -> x2bt [b*513+t][576] cols 0..511, relu
    gemm(x1, w2, b2, nullptr, x2bt, M_, 512, 2048, 0, CE_, 3, 0, 1);
    // subject embedding -> cols 512..575
    emb_kernel<<<(M_ * 64 + 255) / 256, 256, 0, stream>>>(semb, subj, x2bt);

    // pack LSTM weights to bf16 (x1 region is dead now)
    pack_w<<<2048, 256, 0, stream>>>(Whh0, P0);
    pack_w<<<2048, 256, 0, stream>>>(Wih1, P1);
    pack_w<<<2048, 256, 0, stream>>>(Whh1, P2);

    // layer-0 x-projection (time-major output, both biases folded)
    gemm(x2bt, Wih0, bih0, bhh0, pre0, M_, 2048, CE_, CE_, 2048, 0, 2, 0);

    // fused 2-layer LSTM: layer0 step t + layer1 step t-1 per launch (514 launches)
    for (int t = 0; t <= L_; ++t)
        lstm_step_fused<<<256, 256, 0, stream>>>(pre0, P0, P1, P2, bih1, bhh1,
                                                 h0, h1, c0, c1, t);

    // fused q/k/cnt projections (read h1 time-major)
    gemm_qkv<<<dim3((M_ + 63) / 64, 24), 256, 0, stream>>>(h1, qw, kw, cw, qb, kb, cbi,
                                                           qb_f, kb_f, cb_f);

    attn_kernel<<<dim3(L_, H_, B_), 128, 0, stream>>>(qb_f, kb_f, cb_f, rel, attno);

    // fc + BN(train) + relu*scale + residual -> xfin (batch-major)
    gemm(attno, fcw, fcb, nullptr, fco, M_, 512, 512, 512, 512, 0, 0, 0);
    bn_stats<<<512, 256, 0, stream>>>(fco, stats);
    bn_apply<<<(M_ * 512 + 255) / 256, 256, 0, stream>>>(fco, stats, bng, bnb, ascl, h1, xfin);

    // final projection -> d_out [b][128][t] fp32
    gemm(xfin, outw, outb, nullptr, out, M_, 128, 512, 512, 0, 0, 1, 0);
}